// Round 4
// baseline (698.154 us; speedup 1.0000x reference)
//
#include <hip/hip_runtime.h>
#include <hip/hip_bf16.h>
#include <stdint.h>

// XCA (cross-covariance attention), B=8 N=8192 C=384 H=8 Dh=48.
// R4: barrier-free MFMA kernels — fragments loaded global->VGPR directly
// (lane l16=row, q4=16B k-chunk matches MFMA A/B layout), no LDS staging.
// Gram sumsq moved into MFMA (diag of QQ^T/KK^T).

typedef __bf16 bf16_t;
typedef __attribute__((ext_vector_type(8))) __bf16 bf16x8;
typedef __attribute__((ext_vector_type(4))) __bf16 bf16x4;
typedef __attribute__((ext_vector_type(4))) float f32x4;

#define NTOK 8192
#define CDIM 384
#define WH   25165824   // 8*8*48*8192 elements per q/k plane
#define DHN  393216     // 48*8192

__device__ __forceinline__ f32x4 mfma16(bf16x8 a, bf16x8 b, f32x4 c) {
  return __builtin_amdgcn_mfma_f32_16x16x32_bf16(a, b, c, 0, 0, 0);
}

template <bool BF16>
__device__ __forceinline__ bf16x8 load8(const void* p, int idx) {
  if constexpr (BF16) {
    return *(const bf16x8*)((const bf16_t*)p + idx);
  } else {
    const float* f = (const float*)p + idx;
    f32x4 a = *(const f32x4*)f;
    f32x4 b = *(const f32x4*)(f + 4);
    bf16x8 r;
    r[0] = (bf16_t)a[0]; r[1] = (bf16_t)a[1]; r[2] = (bf16_t)a[2]; r[3] = (bf16_t)a[3];
    r[4] = (bf16_t)b[0]; r[5] = (bf16_t)b[1]; r[6] = (bf16_t)b[2]; r[7] = (bf16_t)b[3];
    return r;
  }
}

// ---------------- K0: probe dtype (block 0) + zero fp32 accumulators ----------------
__global__ void k_init(const uint32_t* __restrict__ X, int* __restrict__ flag,
                       float* __restrict__ acc, int n) {
  __shared__ int cnt;
  int i = blockIdx.x * 256 + threadIdx.x;
  if (i < n) acc[i] = 0.f;
  if (blockIdx.x == 0) {
    if (threadIdx.x == 0) cnt = 0;
    __syncthreads();
    const uint32_t w = X[threadIdx.x];
    const int e = (int)((w >> 7) & 0xFF);  // exponent of low-16 as bf16
    atomicAdd(&cnt, (e >= 110 && e <= 131) ? 1 : 0);
    __syncthreads();
    if (threadIdx.x == 0) *flag = (cnt >= 128) ? 1 : 0;
  }
}

// ---------------- K1: qkv = x @ w_qkv^T ----------------
// A = w_qkv (1152x384 rows j), B = x (65536x384 rows m). D[j][m].
// Grid (512 m-tiles, 3 jt-groups). which = blockIdx.y (uniform).
// Fragments loaded straight from global (no LDS, no barriers).
template <bool BF16>
__device__ __forceinline__ void gemm_qkv_body(const void* __restrict__ X,
                                              const void* __restrict__ Wqkv,
                                              bf16_t* __restrict__ qkv) {
  const int tid = threadIdx.x;
  const int lane = tid & 63;
  const int wr = tid >> 7, wc = (tid >> 6) & 1;
  const int q4 = lane >> 4, l16 = lane & 15;
  const int rowB0 = blockIdx.x * 128;
  const int which = blockIdx.y;  // 0=q 1=k 2=v

  int brow[4];
#pragma unroll
  for (int j = 0; j < 4; j++)
    brow[j] = (rowB0 + wc * 64 + j * 16 + l16) * CDIM + q4 * 8;

  for (int jj = 0; jj < 3; jj++) {
    const int jt = which * 3 + jj;
    const int rowA0 = jt * 128;
    int arow[4];
#pragma unroll
    for (int i = 0; i < 4; i++)
      arow[i] = (rowA0 + wr * 64 + i * 16 + l16) * CDIM + q4 * 8;

    f32x4 acc[4][4];
#pragma unroll
    for (int i = 0; i < 4; i++)
#pragma unroll
      for (int j = 0; j < 4; j++) acc[i][j] = (f32x4){0.f, 0.f, 0.f, 0.f};

#pragma unroll 2
    for (int k0 = 0; k0 < CDIM; k0 += 32) {
      bf16x8 af[4], bfr[4];
#pragma unroll
      for (int i = 0; i < 4; i++) af[i] = load8<BF16>(Wqkv, arow[i] + k0);
#pragma unroll
      for (int j = 0; j < 4; j++) bfr[j] = load8<BF16>(X, brow[j] + k0);
#pragma unroll
      for (int i = 0; i < 4; i++)
#pragma unroll
        for (int j = 0; j < 4; j++) acc[i][j] = mfma16(af[i], bfr[j], acc[i][j]);
    }

#pragma unroll
    for (int i = 0; i < 4; i++) {
#pragma unroll
      for (int j = 0; j < 4; j++) {
        const int mg = rowB0 + wc * 64 + j * 16 + l16;
        if (which < 2) {
#pragma unroll
          for (int r = 0; r < 4; r++) {
            const int jg = rowA0 + wr * 64 + i * 16 + q4 * 4 + r;
            const int rin = jg - which * 384;
            const int h = rin / 48, dh = rin - h * 48;
            const int addr = which * WH + (((mg >> 13) << 3) + h) * DHN + dh * NTOK + (mg & 8191);
            qkv[addr] = (bf16_t)acc[i][j][r];
          }
        } else {
          const int rin0 = rowA0 + wr * 64 + i * 16 + q4 * 4 - 768;
          bf16x4 v4;
#pragma unroll
          for (int r = 0; r < 4; r++) v4[r] = (bf16_t)acc[i][j][r];
          *(bf16x4*)&qkv[2 * WH + mg * CDIM + rin0] = v4;
        }
      }
    }
  }
}

__global__ __launch_bounds__(256, 3) void k_gemm_qkv(
    const void* __restrict__ X, const void* __restrict__ Wqkv,
    bf16_t* __restrict__ qkv, const int* __restrict__ flagp) {
  if (*flagp) gemm_qkv_body<true>(X, Wqkv, qkv);
  else        gemm_qkv_body<false>(X, Wqkv, qkv);
}

// ---------------- K2: Gram S=Q K^T + sumsq via MFMA diag ----------------
// grid (8 n-splits, 64 bh). Wave w owns n-slice w*32 within each 128-chunk.
// No staging LDS; LDS only for the cross-wave reduction tail.
__global__ __launch_bounds__(256, 2) void k_gram(
    const bf16_t* __restrict__ qkv, float* __restrict__ S_acc, float* __restrict__ ssq_acc) {
  __shared__ float red[9312];           // 4 waves x 2304 + 96 ssq
  float* ssq_sm = red + 9216;

  const int tid = threadIdx.x;
  const int wave = tid >> 6, lane = tid & 63, q4 = lane >> 4, l16 = lane & 15;
  const int s = blockIdx.x, bh = blockIdx.y;
  const bf16_t* Qg = qkv + bh * DHN;
  const bf16_t* Kg = qkv + WH + bh * DHN;

  if (tid < 96) ssq_sm[tid] = 0.f;

  f32x4 acc[3][3], aqq[3], akk[3];
#pragma unroll
  for (int i = 0; i < 3; i++) {
    aqq[i] = (f32x4){0.f, 0.f, 0.f, 0.f};
    akk[i] = (f32x4){0.f, 0.f, 0.f, 0.f};
#pragma unroll
    for (int j = 0; j < 3; j++) acc[i][j] = (f32x4){0.f, 0.f, 0.f, 0.f};
  }

  const int colbase = s * 1024 + wave * 32 + q4 * 8;
#pragma unroll 2
  for (int t0 = 0; t0 < 8; t0++) {
    const int nc = colbase + t0 * 128;
    bf16x8 qf[3], kf[3];
#pragma unroll
    for (int i = 0; i < 3; i++) {
      qf[i] = *(const bf16x8*)(Qg + (i * 16 + l16) * NTOK + nc);
      kf[i] = *(const bf16x8*)(Kg + (i * 16 + l16) * NTOK + nc);
    }
#pragma unroll
    for (int i = 0; i < 3; i++) {
      aqq[i] = mfma16(qf[i], qf[i], aqq[i]);
      akk[i] = mfma16(kf[i], kf[i], akk[i]);
#pragma unroll
      for (int j = 0; j < 3; j++) acc[i][j] = mfma16(qf[i], kf[j], acc[i][j]);
    }
  }

  __syncthreads();  // ssq_sm init visible before atomics
  // diag of QQ^T / KK^T = sumsq; lane holds diag iff l16 == q4*4+r
#pragma unroll
  for (int i = 0; i < 3; i++) {
#pragma unroll
    for (int r = 0; r < 4; r++) {
      if (l16 == q4 * 4 + r) {
        atomicAdd(&ssq_sm[i * 16 + q4 * 4 + r], aqq[i][r]);
        atomicAdd(&ssq_sm[48 + i * 16 + q4 * 4 + r], akk[i][r]);
      }
    }
  }
#pragma unroll
  for (int i = 0; i < 3; i++)
#pragma unroll
    for (int j = 0; j < 3; j++)
#pragma unroll
      for (int r = 0; r < 4; r++)
        red[wave * 2304 + (i * 3 + j) * 256 + lane * 4 + r] = acc[i][j][r];
  __syncthreads();
  for (int idx = tid; idx < 2304; idx += 256) {
    const float v = red[idx] + red[2304 + idx] + red[4608 + idx] + red[6912 + idx];
    const int tile = idx >> 8, ln = (idx >> 2) & 63, r = idx & 3;
    const int i = tile / 3, j = tile - i * 3;
    const int d = i * 16 + ((ln >> 4) << 2) + r;
    const int e = j * 16 + (ln & 15);
    atomicAdd(&S_acc[bh * 2304 + d * 48 + e], v);
  }
  if (tid < 96) atomicAdd(&ssq_acc[bh * 96 + tid], ssq_sm[tid]);
}

// ---------------- K3: softmax(S / (|q_d||k_e|)) ----------------
__global__ void k_softmax(const float* __restrict__ S_acc, const float* __restrict__ ssq_acc,
                          float* __restrict__ attn_f) {
  __shared__ float invk_sm[48];
  const int bh = blockIdx.x, d = threadIdx.x;
  if (d < 48) invk_sm[d] = 1.f / fmaxf(sqrtf(ssq_acc[bh * 96 + 48 + d]), 1e-12f);
  __syncthreads();
  if (d < 48) {
    const float invq = 1.f / fmaxf(sqrtf(ssq_acc[bh * 96 + d]), 1e-12f);
    float lg[48], mx = -1e30f;
#pragma unroll
    for (int e = 0; e < 48; e++) {
      lg[e] = S_acc[bh * 2304 + d * 48 + e] * invq * invk_sm[e];
      mx = fmaxf(mx, lg[e]);
    }
    float ssum = 0.f;
#pragma unroll
    for (int e = 0; e < 48; e++) { lg[e] = expf(lg[e] - mx); ssum += lg[e]; }
    const float inv = 1.f / ssum;
#pragma unroll
    for (int e = 0; e < 48; e++) attn_f[bh * 2304 + d * 48 + e] = lg[e] * inv;
  }
}

// ---------------- K4: Weff_b[c'][h*48+e] = sum_d Wp[c'][h*48+d] attn[bh][d][e] ------
__global__ __launch_bounds__(256, 2) void k_weff(
    const float* __restrict__ attn_f, const void* __restrict__ Wp,
    bf16_t* __restrict__ Weff, const int* __restrict__ flagp) {
  __shared__ float attn_sm[2304];
  const int isb = *flagp;
  const int b = blockIdx.x >> 3, h = blockIdx.x & 7;
  const int tid = threadIdx.x, bh = b * 8 + h;
  for (int i = tid; i < 2304; i += 256) attn_sm[i] = attn_f[bh * 2304 + i];
  __syncthreads();
  const int cb = tid >> 3, eb = tid & 7;
  float res[12][6];
#pragma unroll
  for (int u = 0; u < 12; u++)
#pragma unroll
    for (int v = 0; v < 6; v++) res[u][v] = 0.f;

  for (int d8 = 0; d8 < 6; d8++) {
    bf16x8 wv[12];
#pragma unroll
    for (int u = 0; u < 12; u++) {
      const int idx = (cb * 12 + u) * CDIM + h * 48 + d8 * 8;
      wv[u] = isb ? load8<true>(Wp, idx) : load8<false>(Wp, idx);
    }
#pragma unroll
    for (int dd = 0; dd < 8; dd++) {
      float wf[12];
#pragma unroll
      for (int u = 0; u < 12; u++) wf[u] = (float)wv[u][dd];
      const int d = d8 * 8 + dd;
#pragma unroll
      for (int v = 0; v < 6; v++) {
        const float a = attn_sm[d * 48 + eb * 6 + v];
#pragma unroll
        for (int u = 0; u < 12; u++) res[u][v] += wf[u] * a;
      }
    }
  }
#pragma unroll
  for (int u = 0; u < 12; u++)
#pragma unroll
    for (int v = 0; v < 6; v++)
      Weff[b * 147456 + (cb * 12 + u) * CDIM + h * 48 + eb * 6 + v] = (bf16_t)res[u][v];
}

// ---------------- K5: out[b,n,c'] = sum_c Weff_b[c'][c] V[b,n,c] + bias[c'] --------
// Grid (64 n-tiles, 8 b); ct loop inside. Barrier-free direct fragment loads.
__global__ __launch_bounds__(256, 3) void k_gemm_out(
    const bf16_t* __restrict__ Weff, const bf16_t* __restrict__ qkv,
    const void* __restrict__ bias, void* __restrict__ out, const int* __restrict__ flagp) {
  const int isb = *flagp;
  const int tid = threadIdx.x;
  const int lane = tid & 63;
  const int wr = tid >> 7, wc = (tid >> 6) & 1;
  const int q4 = lane >> 4, l16 = lane & 15;
  const int b = blockIdx.y;
  const int rowB0 = blockIdx.x * 128;
  const bf16_t* Abase = Weff + b * 147456;
  const bf16_t* Bbase = qkv + 2 * WH + b * (NTOK * CDIM);

  int brow[4];
#pragma unroll
  for (int j = 0; j < 4; j++)
    brow[j] = (rowB0 + wc * 64 + j * 16 + l16) * CDIM + q4 * 8;

  for (int ct = 0; ct < 3; ct++) {
    const int rowA0 = ct * 128;
    int arow[4];
#pragma unroll
    for (int i = 0; i < 4; i++)
      arow[i] = (rowA0 + wr * 64 + i * 16 + l16) * CDIM + q4 * 8;

    f32x4 acc[4][4];
#pragma unroll
    for (int i = 0; i < 4; i++)
#pragma unroll
      for (int j = 0; j < 4; j++) acc[i][j] = (f32x4){0.f, 0.f, 0.f, 0.f};

#pragma unroll 2
    for (int k0 = 0; k0 < CDIM; k0 += 32) {
      bf16x8 af[4], bfr[4];
#pragma unroll
      for (int i = 0; i < 4; i++) af[i] = *(const bf16x8*)(Abase + arow[i] + k0);
#pragma unroll
      for (int j = 0; j < 4; j++) bfr[j] = *(const bf16x8*)(Bbase + brow[j] + k0);
#pragma unroll
      for (int i = 0; i < 4; i++)
#pragma unroll
        for (int j = 0; j < 4; j++) acc[i][j] = mfma16(af[i], bfr[j], acc[i][j]);
    }

#pragma unroll
    for (int i = 0; i < 4; i++) {
      const int cg0 = rowA0 + wr * 64 + i * 16 + q4 * 4;
      float bv[4];
#pragma unroll
      for (int r = 0; r < 4; r++)
        bv[r] = isb ? (float)((const bf16_t*)bias)[cg0 + r] : ((const float*)bias)[cg0 + r];
#pragma unroll
      for (int j = 0; j < 4; j++) {
        const int ng = rowB0 + wc * 64 + j * 16 + l16;
        if (isb) {
          bf16x4 v4;
#pragma unroll
          for (int r = 0; r < 4; r++) v4[r] = (bf16_t)(acc[i][j][r] + bv[r]);
          *(bf16x4*)&((bf16_t*)out)[(b * NTOK + ng) * CDIM + cg0] = v4;
        } else {
          f32x4 v4;
#pragma unroll
          for (int r = 0; r < 4; r++) v4[r] = acc[i][j][r] + bv[r];
          *(f32x4*)&((float*)out)[(b * NTOK + ng) * CDIM + cg0] = v4;
        }
      }
    }
  }
}

extern "C" void kernel_launch(void* const* d_in, const int* in_sizes, int n_in,
                              void* d_out, int out_size, void* d_ws, size_t ws_size,
                              hipStream_t stream) {
  (void)in_sizes; (void)n_in; (void)out_size; (void)ws_size;
  const void* X    = d_in[0];
  const void* Wqkv = d_in[1];
  const void* Wp   = d_in[2];
  const void* bias = d_in[3];

  char* ws = (char*)d_ws;
  bf16_t* qkv    = (bf16_t*)ws;                     // 3*WH bf16 = 150,994,944 B
  float*  S_acc  = (float*)(ws + 150994944);        // 64*2304 f32
  float*  ssq    = (float*)(ws + 151584768);        // 64*96 f32
  float*  attn_f = (float*)(ws + 151609344);        // 64*2304 f32
  bf16_t* Weff   = (bf16_t*)(ws + 152199168);       // 8*384*384 bf16
  int*    flag   = (int*)(ws + 154558464);

  k_init<<<dim3(600), 256, 0, stream>>>((const uint32_t*)X, flag, S_acc, 153600);
  k_gemm_qkv<<<dim3(512, 3), 256, 0, stream>>>(X, Wqkv, qkv, flag);
  k_gram<<<dim3(8, 64), 256, 0, stream>>>(qkv, S_acc, ssq);
  k_softmax<<<dim3(64), 64, 0, stream>>>(S_acc, ssq, attn_f);
  k_weff<<<dim3(64), 256, 0, stream>>>(attn_f, Wp, Weff, flag);
  k_gemm_out<<<dim3(64, 8), 256, 0, stream>>>(Weff, qkv, bias, d_out, flag);
}